// Round 5
// baseline (259.933 us; speedup 1.0000x reference)
//
#include <hip/hip_runtime.h>
#include <math.h>

#define BATCH 8
#define HH 1024
#define WW 1024
#define CC 3
#define MTOT (HH*WW*CC)          // 3145728 per batch
#define RSEL 1572864u            // ceil(M/2)

#define WCAP 131072u             // per-batch window record capacity (expect ~39K used)
#define LCAP 1024u               // per-block LDS record capacity (expect ~307 used, 8 quads/thread)
#define P1B  1024                // pass1 threshold blocks (128 per batch)
#define QPT  8                   // pixel-quads per thread

// window: |x| < 2^-6. Median of 3.1M N(0,1) samples is within ~8e-3 (11 sigma).
// Window holds ~39K elems/batch. Exact per-batch fallback in K2/K3 if it ever misses.
#define U_HI 0xBC800000u         // fmap(+2^-6)
#define U_LO 0x437FFFFFu         // fmap(-2^-6)

// native vector types for __builtin_nontemporal_store (HIP_vector_type is rejected)
typedef float nfloat4 __attribute__((ext_vector_type(4)));
typedef float nfloat2 __attribute__((ext_vector_type(2)));

// ---- ws layout (bytes). wcnt+chib (first 1024 B) need zero-init; rest written unconditionally.
#define WS_WCNT_OFF  0u          // 8 u32 @ stride 64B : per-batch window counts (atomic)
#define WS_CHI_OFF   512u        // 8 u32 @ stride 64B : per-batch high counts (atomic)
#define WS_NPART_OFF 1024u       // 256 f32 : znorm partials
#define WS_THR_OFF   2048u       // 8 u32 : thresholds (u-space)
#define WS_FB_OFF    2112u       // 8 u32 : per-batch fallback flags
#define WS_NORM_OFF  2176u       // 1 f32 : total norm
#define WS_WU_OFF    4096u       // 8*WCAP u32 = 4 MB window u-values (SoA)
#define WS_WP_OFF    4198400u    // 8*WCAP u32 = 4 MB window output positions (SoA)

// refine: 3 wave-privatized histogram copies, +1 stride to decorrelate banks
#define NCOPY 3
#define HSTRIDE 4097

__device__ __forceinline__ unsigned int fmap(float x) {
    unsigned int b = __float_as_uint(x);
    return (b & 0x80000000u) ? ~b : (b | 0x80000000u);
}

__device__ __forceinline__ void nt_store4(float4 v, float4* p) {
    nfloat4 t; t.x = v.x; t.y = v.y; t.z = v.z; t.w = v.w;
    __builtin_nontemporal_store(t, (nfloat4*)p);
}
__device__ __forceinline__ void nt_store2(float2 v, float2* p) {
    nfloat2 t; t.x = v.x; t.y = v.y;
    __builtin_nontemporal_store(t, (nfloat2*)p);
}

// Shared transpose-threshold body for K3's exact fallback path.
__device__ __forceinline__ void thresh_row_quad(const float* __restrict__ Yb,
                                                float* __restrict__ outb,
                                                int h, int w4, unsigned int tu) {
    const float4* src = (const float4*)(Yb + ((size_t)h * WW + (size_t)w4 * 4) * CC);
    float4 a0 = src[0], a1 = src[1], a2 = src[2];
    float4 r0, r1, r2;
    r0.x = (fmap(a0.x) >= tu) ? 1.f : 0.f;
    r0.y = (fmap(a0.w) >= tu) ? 1.f : 0.f;
    r0.z = (fmap(a1.z) >= tu) ? 1.f : 0.f;
    r0.w = (fmap(a2.y) >= tu) ? 1.f : 0.f;
    r1.x = (fmap(a0.y) >= tu) ? 1.f : 0.f;
    r1.y = (fmap(a1.x) >= tu) ? 1.f : 0.f;
    r1.z = (fmap(a1.w) >= tu) ? 1.f : 0.f;
    r1.w = (fmap(a2.z) >= tu) ? 1.f : 0.f;
    r2.x = (fmap(a0.z) >= tu) ? 1.f : 0.f;
    r2.y = (fmap(a1.y) >= tu) ? 1.f : 0.f;
    r2.z = (fmap(a2.x) >= tu) ? 1.f : 0.f;
    r2.w = (fmap(a2.w) >= tu) ? 1.f : 0.f;
    size_t base = (size_t)h * WW;
    ((float4*)(outb + base))[w4]                        = r0;
    ((float4*)(outb + base + (size_t)HH * WW))[w4]      = r1;
    ((float4*)(outb + base + (size_t)2 * HH * WW))[w4]  = r2;
}

// ---- K1: single full pass over Y. Blocks [0,P1B): each thread processes 8
// pixel-quads (96 floats); ALL 24 float4 loads issued up-front for MLP.
// Speculative threshold write (u>=U_HI -> 1, u<U_LO -> 0, window -> 0 + record).
// Non-temporal stores keep out from evicting Y's L3 residency.
// Blocks [P1B,P1B+256): znorm partials over zabs.
__global__ void pass1_kernel(const float* __restrict__ Y,
                             const float* __restrict__ zabs,
                             float* __restrict__ out,
                             unsigned int* __restrict__ wu,
                             unsigned int* __restrict__ wpos,
                             unsigned int* __restrict__ wcnt,
                             unsigned int* __restrict__ chib,
                             float* __restrict__ npart) {
    const int tid = threadIdx.x;

    if (blockIdx.x >= P1B) {
        // znorm partial: sum zabs^2 over HH*WW, one partial per block (256 blocks)
        const int bx = blockIdx.x - P1B;
        float s = 0.f;
        const int n4z = HH * WW / 4;                 // 262144
        for (int i = bx * 256 + tid; i < n4z; i += 256 * 256) {  // 4 iters
            float4 v = ((const float4*)zabs)[i];
            s += v.x * v.x + v.y * v.y + v.z * v.z + v.w * v.w;
        }
        for (int d = 32; d > 0; d >>= 1) s += __shfl_down(s, d);
        __shared__ float ls[4];
        if ((tid & 63) == 0) ls[tid >> 6] = s;
        __syncthreads();
        if (tid == 0) npart[bx] = ls[0] + ls[1] + ls[2] + ls[3];
        return;
    }

    __shared__ unsigned int lu[LCAP];
    __shared__ unsigned int lp[LCAP];
    __shared__ unsigned int lcnt;
    __shared__ unsigned int red[4];
    __shared__ unsigned int gbase_s;
    if (tid == 0) lcnt = 0u;
    __syncthreads();

    const int blk = blockIdx.x;                      // [0, P1B): 128 blocks per batch
    const int b = blk >> 7;                          // block-uniform
    const int p0 = (blk & 127) * 2048 + tid;         // within-batch quad index base
    const float* Yb = Y + (size_t)b * MTOT;
    float* outb = out + (size_t)b * MTOT;
    float4* o4 = (float4*)outb;

    // issue all 24 loads before any use: 24 independent vmem ops in flight
    float4 A0[QPT], A1[QPT], A2[QPT];
#pragma unroll
    for (int it = 0; it < QPT; it++) {
        int p = p0 + it * 256;
        const float4* src = (const float4*)(Yb + (size_t)p * 12);
        A0[it] = src[0]; A1[it] = src[1]; A2[it] = src[2];
    }

    unsigned int hcnt = 0u;

#pragma unroll
    for (int it = 0; it < QPT; it++) {
        const int p = p0 + it * 256;
        const unsigned int rowbase = (unsigned int)(4 * p);
        float4 a0 = A0[it], a1 = A1[it], a2 = A2[it];
        float4 r0, r1, r2;

#define SPEC(val, c, k, dst) do { \
        unsigned int u = fmap(val); \
        dst = (u >= U_HI) ? 1.f : 0.f; \
        if (u >= U_HI) hcnt++; \
        else if (u >= U_LO) { \
            unsigned int pp = atomicAdd(&lcnt, 1u); \
            if (pp < LCAP) { lu[pp] = u; lp[pp] = (unsigned int)((c) * HH * WW) + rowbase + (unsigned int)(k); } \
        } \
    } while (0)

        SPEC(a0.x, 0, 0, r0.x); SPEC(a0.w, 0, 1, r0.y); SPEC(a1.z, 0, 2, r0.z); SPEC(a2.y, 0, 3, r0.w);
        SPEC(a0.y, 1, 0, r1.x); SPEC(a1.x, 1, 1, r1.y); SPEC(a1.w, 1, 2, r1.z); SPEC(a2.z, 1, 3, r1.w);
        SPEC(a0.z, 2, 0, r2.x); SPEC(a1.y, 2, 1, r2.y); SPEC(a2.x, 2, 2, r2.z); SPEC(a2.w, 2, 3, r2.w);
#undef SPEC

        nt_store4(r0, &o4[p]);
        nt_store4(r1, &o4[262144 + p]);
        nt_store4(r2, &o4[524288 + p]);
    }

    // block reductions: one global atomic each for count + high-count
    __syncthreads();
    unsigned int n = lcnt;                           // block-uniform
    unsigned int nc = (n > LCAP) ? LCAP : n;
    if (tid == 0) {
        // overflow (never expected: mean 307, cap 1024) poisons wcnt -> fallback
        unsigned int add = (n > LCAP) ? (WCAP + 1u) : n;
        gbase_s = atomicAdd(&wcnt[b * 16], add);
    }
    for (int d = 32; d > 0; d >>= 1) hcnt += __shfl_down(hcnt, d);
    if ((tid & 63) == 0) red[tid >> 6] = hcnt;
    __syncthreads();
    if (tid == 0) atomicAdd(&chib[b * 16], red[0] + red[1] + red[2] + red[3]);

    unsigned int gbase = gbase_s;
    unsigned int* wub = wu + (size_t)b * WCAP;
    unsigned int* wpb = wpos + (size_t)b * WCAP;
    for (unsigned int j = tid; j < nc; j += 256u) {
        unsigned int q = gbase + j;
        if (q < WCAP) { wub[q] = lu[j]; wpb[q] = lp[j]; }
    }
}

// ---- K2: blocks 0..7 = per-batch 3-level radix select over the contiguous
// per-batch window u-array; 3 wave-privatized hist copies kill same-address
// LDS atomic serialization (window values concentrate in ~16 exponent bins).
// Block 8 = norm finalize.
__global__ void __launch_bounds__(1024) refine_kernel(
        const float* __restrict__ Y,
        const unsigned int* __restrict__ wu,
        const unsigned int* __restrict__ wcnt,
        const unsigned int* __restrict__ chib,
        const float* __restrict__ npart,
        unsigned int* __restrict__ thr,
        unsigned int* __restrict__ fbflag,
        float* __restrict__ normsum) {
    const int tid = threadIdx.x;

    if (blockIdx.x == 8) {
        float s = (tid < 256) ? npart[tid] : 0.f;
        for (int d = 32; d > 0; d >>= 1) s += __shfl_down(s, d);
        __shared__ float ls[16];
        if ((tid & 63) == 0) ls[tid >> 6] = s;
        __syncthreads();
        if (tid == 0) {
            float t = 0.f;
            for (int i = 0; i < 16; i++) t += ls[i];
            *normsum = t;
        }
        return;
    }

    __shared__ unsigned int hist[NCOPY * HSTRIDE];   // 48 KB
    __shared__ unsigned int waveSums[16];
    __shared__ unsigned int selBin, selBase;
    const int b = blockIdx.x;
    const int lane = tid & 63, wid = tid >> 6;
    const int hc = (wid % NCOPY) * HSTRIDE;          // this wave's hist copy base

    const unsigned int wc = wcnt[b * 16];
    const unsigned int Ch = chib[b * 16];
    const int fb = (wc > WCAP) || (Ch >= RSEL) || (Ch + wc < RSEL);
    unsigned int target = fb ? RSEL : (RSEL - Ch);
    const unsigned int wcg = (wc > WCAP) ? WCAP : wc;
    const unsigned int* wp = wu + (size_t)b * WCAP;
    const float* Yb = Y + (size_t)b * MTOT;

    unsigned int d1 = 0, d2 = 0;

    for (int level = 0; level < 3; level++) {
        const int nb  = (level < 2) ? 4096 : 256;
        const int bpt = (level < 2) ? 4 : 1;
        for (int i = tid; i < NCOPY * HSTRIDE; i += 1024) hist[i] = 0u;
        if (tid == 0) { selBin = 0u; selBase = 0u; }
        __syncthreads();

#define HISTO(u) do { \
            if (level == 0) atomicAdd(&hist[hc + ((u) >> 20)], 1u); \
            else if (level == 1) { if (((u) >> 20) == d1) atomicAdd(&hist[hc + (((u) >> 8) & 0xFFFu)], 1u); } \
            else { if (((u) >> 8) == ((d1 << 12) | d2)) atomicAdd(&hist[hc + ((u) & 0xFFu)], 1u); } \
        } while (0)

        if (fb) {
            for (unsigned int i = tid; i < (unsigned int)MTOT; i += 1024u) {
                unsigned int u = fmap(Yb[i]);
                HISTO(u);
            }
        } else {
            for (unsigned int i = tid; i < wcg; i += 1024u) {
                unsigned int u = wp[i];
                HISTO(u);
            }
        }
#undef HISTO
        __syncthreads();
        // descending scan + pick (merge the 3 copies at read time)
        unsigned int c[4] = {0u, 0u, 0u, 0u};
        unsigned int s = 0u;
        const int nthr = nb / bpt;
        if (tid < nthr)
            for (int k = 0; k < bpt; k++) {
                int bin = nb - 1 - (tid * bpt + k);
                c[k] = hist[bin] + hist[HSTRIDE + bin] + hist[2 * HSTRIDE + bin];
                s += c[k];
            }
        unsigned int incl = s;
        for (int d = 1; d < 64; d <<= 1) {
            unsigned int v = __shfl_up(incl, d);
            if (lane >= d) incl += v;
        }
        if (lane == 63) waveSums[wid] = incl;
        __syncthreads();
        if (tid < 16) {
            unsigned int w = waveSums[tid];
            for (int d = 1; d < 16; d <<= 1) {
                unsigned int v = __shfl_up(w, d);
                if (tid >= d) w += v;
            }
            waveSums[tid] = w;
        }
        __syncthreads();
        incl += (wid > 0) ? waveSums[wid - 1] : 0u;
        unsigned int excl = incl - s;
        if (s > 0u && excl < target && incl >= target) {
            unsigned int run = excl;
            for (int k = 0; k < bpt; k++) {
                if (run + c[k] >= target) {
                    selBin = (unsigned int)(nb - 1 - (tid * bpt + k));
                    selBase = run;
                    break;
                }
                run += c[k];
            }
        }
        __syncthreads();
        if (level == 0) d1 = selBin;
        else if (level == 1) d2 = selBin;
        target -= selBase;
        __syncthreads();
    }
    if (tid == 0) {
        thr[b] = (d1 << 20) | (d2 << 8) | selBin;
        fbflag[b] = (unsigned int)fb;
    }
}

// ---- K3: blocks [0,2048) Z0 write; blocks [2048,4096) window fixup
// (or per-batch full re-threshold if that batch hit fallback).
__global__ void fixup_z_kernel(const float* __restrict__ Y,
                               const unsigned int* __restrict__ wu,
                               const unsigned int* __restrict__ wpos,
                               const unsigned int* __restrict__ wcnt,
                               const unsigned int* __restrict__ thr,
                               const unsigned int* __restrict__ fbflag,
                               const float* __restrict__ zabs,
                               const float* __restrict__ zang,
                               const float* __restrict__ normsum,
                               float* __restrict__ out,
                               float* __restrict__ outz, int interleaved) {
    const int tid = threadIdx.x;
    if (blockIdx.x < 2048) {
        int i = blockIdx.x * 256 + tid;              // [0, HH*WW/2)
        float inv = 1.0f / sqrtf(*normsum);
        float2 a = ((const float2*)zabs)[i];
        float2 g = ((const float2*)zang)[i];
        float s0, c0, s1, c1;
        __sincosf(g.x, &s0, &c0);
        __sincosf(g.y, &s1, &c1);
        if (interleaved) {
            float4 o;
            o.x = a.x * c0 * inv; o.y = a.x * s0 * inv;
            o.z = a.y * c1 * inv; o.w = a.y * s1 * inv;
            nt_store4(o, &((float4*)outz)[i]);
        } else {
            float2 o;
            o.x = a.x * c0 * inv; o.y = a.y * c1 * inv;
            nt_store2(o, &((float2*)outz)[i]);
        }
    } else {
        const int j = blockIdx.x - 2048;             // [0, 2048): 256 blocks per batch
        const int b = j >> 8;
        const unsigned int tu = thr[b];
        float* outb = out + (size_t)b * MTOT;
        if (fbflag[b]) {
            // exact fallback: full re-threshold + transpose for this batch
            const float* Yb = Y + (size_t)b * MTOT;
            for (int q = (j & 255); q < 1024; q += 256) {        // 4 sub-rows of work
                int pq = q * 256 + tid;                          // [0, 262144)
                thresh_row_quad(Yb, outb, pq >> 8, pq & 255, tu);
            }
        } else {
            const unsigned int wc = wcnt[b * 16];                // <= WCAP in non-fb mode
            const unsigned int* wub = wu + (size_t)b * WCAP;
            const unsigned int* wpb = wpos + (size_t)b * WCAP;
            for (unsigned int i = (unsigned int)(j & 255) * 256u + tid; i < wc; i += 65536u) {
                unsigned int u = wub[i];
                unsigned int pos = wpb[i];
                outb[pos] = (u >= tu) ? 1.f : 0.f;
            }
        }
    }
}

extern "C" void kernel_launch(void* const* d_in, const int* in_sizes, int n_in,
                              void* d_out, int out_size, void* d_ws, size_t ws_size,
                              hipStream_t stream) {
    const float* Y    = (const float*)d_in[0];
    const float* zabs = (const float*)d_in[1];
    const float* zang = (const float*)d_in[2];
    float* out = (float*)d_out;

    unsigned char* ws = (unsigned char*)d_ws;
    unsigned int* wcnt  = (unsigned int*)(ws + WS_WCNT_OFF);
    unsigned int* chib  = (unsigned int*)(ws + WS_CHI_OFF);
    float*        npart = (float*)(ws + WS_NPART_OFF);
    unsigned int* thr   = (unsigned int*)(ws + WS_THR_OFF);
    unsigned int* fbf   = (unsigned int*)(ws + WS_FB_OFF);
    float*        norm  = (float*)(ws + WS_NORM_OFF);
    unsigned int* wu    = (unsigned int*)(ws + WS_WU_OFF);
    unsigned int* wpos  = (unsigned int*)(ws + WS_WP_OFF);

    // zero the atomic counters (wcnt @0..512, chib @512..1024)
    (void)hipMemsetAsync(ws, 0, 1024, stream);

    pass1_kernel<<<P1B + 256, 256, 0, stream>>>(Y, zabs, out, wu, wpos, wcnt, chib, npart);
    refine_kernel<<<9, 1024, 0, stream>>>(Y, wu, wcnt, chib, npart, thr, fbf, norm);

    size_t zoff = (size_t)BATCH * CC * HH * WW;   // 25165824
    int zfloats = out_size - (int)zoff;
    int interleaved = (zfloats >= 2 * HH * WW) ? 1 : 0;
    fixup_z_kernel<<<2048 + 2048, 256, 0, stream>>>(
        Y, wu, wpos, wcnt, thr, fbf, zabs, zang, norm, out, out + zoff, interleaved);
}

// Round 6
// 256.885 us; speedup vs baseline: 1.0119x; 1.0119x over previous
//
#include <hip/hip_runtime.h>
#include <math.h>

#define BATCH 8
#define HH 1024
#define WW 1024
#define CC 3
#define MTOT (HH*WW*CC)          // 3145728 per batch
#define RSEL 1572864u            // ceil(M/2)

#define WCAP 131072u             // per-batch window record capacity (expect ~39K used)
#define LCAP 1024u               // per-block LDS record capacity (expect ~153 used)
#define P1B  2048                // pass1 threshold blocks (256 per batch)
#define QPT  4                   // pixel-quads per thread (48 floats)

// window: |x| < 2^-6. Median of 3.1M N(0,1) samples is within ~8e-3 (11 sigma).
// Window holds ~39K elems/batch. Exact per-batch fallback in K2/K3 if it ever misses.
#define U_HI 0xBC800000u         // fmap(+2^-6)
#define U_LO 0x437FFFFFu         // fmap(-2^-6)

// native vector types for __builtin_nontemporal_store (HIP_vector_type is rejected)
typedef float nfloat4 __attribute__((ext_vector_type(4)));
typedef float nfloat2 __attribute__((ext_vector_type(2)));

// ---- ws layout (bytes). wcnt+chib (first 1024 B) need zero-init; rest written unconditionally.
#define WS_WCNT_OFF  0u          // 8 u32 @ stride 64B : per-batch window counts (atomic)
#define WS_CHI_OFF   512u        // 8 u32 @ stride 64B : per-batch high counts (atomic)
#define WS_NPART_OFF 1024u       // 256 f32 : znorm partials
#define WS_THR_OFF   2048u       // 8 u32 : thresholds (u-space)
#define WS_FB_OFF    2112u       // 8 u32 : per-batch fallback flags
#define WS_NORM_OFF  2176u       // 1 f32 : total norm
#define WS_WU_OFF    4096u       // 8*WCAP u32 = 4 MB window u-values (SoA)
#define WS_WP_OFF    4198400u    // 8*WCAP u32 = 4 MB window output positions (SoA)

// refine: 3 wave-privatized histogram copies, +1 stride to decorrelate banks
#define NCOPY 3
#define HSTRIDE 4097

__device__ __forceinline__ unsigned int fmap(float x) {
    unsigned int b = __float_as_uint(x);
    return (b & 0x80000000u) ? ~b : (b | 0x80000000u);
}

__device__ __forceinline__ void nt_store4(float4 v, float4* p) {
    nfloat4 t; t.x = v.x; t.y = v.y; t.z = v.z; t.w = v.w;
    __builtin_nontemporal_store(t, (nfloat4*)p);
}
__device__ __forceinline__ void nt_store2(float2 v, float2* p) {
    nfloat2 t; t.x = v.x; t.y = v.y;
    __builtin_nontemporal_store(t, (nfloat2*)p);
}

// Shared transpose-threshold body for K3's exact fallback path.
__device__ __forceinline__ void thresh_row_quad(const float* __restrict__ Yb,
                                                float* __restrict__ outb,
                                                int h, int w4, unsigned int tu) {
    const float4* src = (const float4*)(Yb + ((size_t)h * WW + (size_t)w4 * 4) * CC);
    float4 a0 = src[0], a1 = src[1], a2 = src[2];
    float4 r0, r1, r2;
    r0.x = (fmap(a0.x) >= tu) ? 1.f : 0.f;
    r0.y = (fmap(a0.w) >= tu) ? 1.f : 0.f;
    r0.z = (fmap(a1.z) >= tu) ? 1.f : 0.f;
    r0.w = (fmap(a2.y) >= tu) ? 1.f : 0.f;
    r1.x = (fmap(a0.y) >= tu) ? 1.f : 0.f;
    r1.y = (fmap(a1.x) >= tu) ? 1.f : 0.f;
    r1.z = (fmap(a1.w) >= tu) ? 1.f : 0.f;
    r1.w = (fmap(a2.z) >= tu) ? 1.f : 0.f;
    r2.x = (fmap(a0.z) >= tu) ? 1.f : 0.f;
    r2.y = (fmap(a1.y) >= tu) ? 1.f : 0.f;
    r2.z = (fmap(a2.x) >= tu) ? 1.f : 0.f;
    r2.w = (fmap(a2.w) >= tu) ? 1.f : 0.f;
    size_t base = (size_t)h * WW;
    ((float4*)(outb + base))[w4]                        = r0;
    ((float4*)(outb + base + (size_t)HH * WW))[w4]      = r1;
    ((float4*)(outb + base + (size_t)2 * HH * WW))[w4]  = r2;
}

// ---- K1: single full pass over Y, two-phase to keep the streaming path
// atomic-free (R2's VGPR=16 showed interleaved LDS atomics defeat load
// batching). Phase A: 12 loads up-front (sched_barrier-pinned), classify 48
// elems into a u64 window mask, NT-store speculative outputs. Phase B (rare):
// one LDS atomicAdd per thread-with-hits + static unrolled record emit.
// Blocks [P1B,P1B+256): znorm partials over zabs.
__global__ void __launch_bounds__(256, 4) pass1_kernel(
                             const float* __restrict__ Y,
                             const float* __restrict__ zabs,
                             float* __restrict__ out,
                             unsigned int* __restrict__ wu,
                             unsigned int* __restrict__ wpos,
                             unsigned int* __restrict__ wcnt,
                             unsigned int* __restrict__ chib,
                             float* __restrict__ npart) {
    const int tid = threadIdx.x;

    if (blockIdx.x >= P1B) {
        // znorm partial: sum zabs^2 over HH*WW, one partial per block (256 blocks)
        const int bx = blockIdx.x - P1B;
        float s = 0.f;
        const int n4z = HH * WW / 4;                 // 262144
        for (int i = bx * 256 + tid; i < n4z; i += 256 * 256) {  // 4 iters
            float4 v = ((const float4*)zabs)[i];
            s += v.x * v.x + v.y * v.y + v.z * v.z + v.w * v.w;
        }
        for (int d = 32; d > 0; d >>= 1) s += __shfl_down(s, d);
        __shared__ float ls[4];
        if ((tid & 63) == 0) ls[tid >> 6] = s;
        __syncthreads();
        if (tid == 0) npart[bx] = ls[0] + ls[1] + ls[2] + ls[3];
        return;
    }

    __shared__ unsigned int lu[LCAP];
    __shared__ unsigned int lp[LCAP];
    __shared__ unsigned int lcnt;
    __shared__ unsigned int red[4];
    __shared__ unsigned int gbase_s;
    if (tid == 0) lcnt = 0u;
    __syncthreads();

    const int blk = blockIdx.x;                      // [0, P1B): 256 blocks per batch
    const int b = blk >> 8;                          // block-uniform
    const int p0 = (blk & 255) * 1024 + tid;         // within-batch quad index base
    const float* Yb = Y + (size_t)b * MTOT;
    float* outb = out + (size_t)b * MTOT;
    float4* o4 = (float4*)outb;

    // ---- Phase A: issue all 12 loads before any use; pin with sched_barrier
    float4 A0[QPT], A1[QPT], A2[QPT];
#pragma unroll
    for (int it = 0; it < QPT; it++) {
        int p = p0 + it * 256;
        const float4* src = (const float4*)(Yb + (size_t)p * 12);
        A0[it] = src[0]; A1[it] = src[1]; A2[it] = src[2];
    }
    __builtin_amdgcn_sched_barrier(0);

    unsigned int hcnt = 0u;
    unsigned long long wmask = 0ull;

#pragma unroll
    for (int it = 0; it < QPT; it++) {
        const int p = p0 + it * 256;
        float4 a0 = A0[it], a1 = A1[it], a2 = A2[it];
        float4 r0, r1, r2;

#define CLS(val, dst, j) do { \
        unsigned int u = fmap(val); \
        bool hi = (u >= U_HI); \
        dst = hi ? 1.f : 0.f; \
        hcnt += hi ? 1u : 0u; \
        if (!hi && u >= U_LO) wmask |= (1ull << (it * 12 + (j))); \
    } while (0)

        CLS(a0.x, r0.x, 0); CLS(a0.w, r0.y, 1); CLS(a1.z, r0.z, 2); CLS(a2.y, r0.w, 3);
        CLS(a0.y, r1.x, 4); CLS(a1.x, r1.y, 5); CLS(a1.w, r1.z, 6); CLS(a2.z, r1.w, 7);
        CLS(a0.z, r2.x, 8); CLS(a1.y, r2.y, 9); CLS(a2.x, r2.z, 10); CLS(a2.w, r2.w, 11);
#undef CLS

        nt_store4(r0, &o4[p]);
        nt_store4(r1, &o4[262144 + p]);
        nt_store4(r2, &o4[524288 + p]);
    }

    // ---- Phase B: rare record emit (~38 threads/block enter), one atomic each
    if (wmask) {
        unsigned int nw = (unsigned int)__popcll(wmask);
        unsigned int base = atomicAdd(&lcnt, nw);
#pragma unroll
        for (int it = 0; it < QPT; it++) {
            const int p = p0 + it * 256;
            const unsigned int rb = (unsigned int)(4 * p);
            float4 a0 = A0[it], a1 = A1[it], a2 = A2[it];
#define EMIT(val, ch, k, j) do { \
            if (wmask & (1ull << (it * 12 + (j)))) { \
                if (base < LCAP) { lu[base] = fmap(val); lp[base] = (unsigned int)((ch) * HH * WW) + rb + (k); } \
                base++; \
            } \
        } while (0)
            EMIT(a0.x, 0, 0, 0); EMIT(a0.w, 0, 1, 1); EMIT(a1.z, 0, 2, 2); EMIT(a2.y, 0, 3, 3);
            EMIT(a0.y, 1, 0, 4); EMIT(a1.x, 1, 1, 5); EMIT(a1.w, 1, 2, 6); EMIT(a2.z, 1, 3, 7);
            EMIT(a0.z, 2, 0, 8); EMIT(a1.y, 2, 1, 9); EMIT(a2.x, 2, 2, 10); EMIT(a2.w, 2, 3, 11);
#undef EMIT
        }
    }

    // block reductions: one global atomic each for count + high-count
    __syncthreads();
    unsigned int n = lcnt;                           // block-uniform
    unsigned int nc = (n > LCAP) ? LCAP : n;
    if (tid == 0) {
        // overflow (never expected: mean 153, cap 1024) poisons wcnt -> fallback
        unsigned int add = (n > LCAP) ? (WCAP + 1u) : n;
        gbase_s = atomicAdd(&wcnt[b * 16], add);
    }
    for (int d = 32; d > 0; d >>= 1) hcnt += __shfl_down(hcnt, d);
    if ((tid & 63) == 0) red[tid >> 6] = hcnt;
    __syncthreads();
    if (tid == 0) atomicAdd(&chib[b * 16], red[0] + red[1] + red[2] + red[3]);

    unsigned int gbase = gbase_s;
    unsigned int* wub = wu + (size_t)b * WCAP;
    unsigned int* wpb = wpos + (size_t)b * WCAP;
    for (unsigned int j = tid; j < nc; j += 256u) {
        unsigned int q = gbase + j;
        if (q < WCAP) { wub[q] = lu[j]; wpb[q] = lp[j]; }
    }
}

// ---- K2: blocks 0..7 = per-batch 3-level radix select over the contiguous
// per-batch window u-array; 3 wave-privatized hist copies kill same-address
// LDS atomic serialization (window values concentrate in ~16 exponent bins).
// Block 8 = norm finalize.
__global__ void __launch_bounds__(1024) refine_kernel(
        const float* __restrict__ Y,
        const unsigned int* __restrict__ wu,
        const unsigned int* __restrict__ wcnt,
        const unsigned int* __restrict__ chib,
        const float* __restrict__ npart,
        unsigned int* __restrict__ thr,
        unsigned int* __restrict__ fbflag,
        float* __restrict__ normsum) {
    const int tid = threadIdx.x;

    if (blockIdx.x == 8) {
        float s = (tid < 256) ? npart[tid] : 0.f;
        for (int d = 32; d > 0; d >>= 1) s += __shfl_down(s, d);
        __shared__ float ls[16];
        if ((tid & 63) == 0) ls[tid >> 6] = s;
        __syncthreads();
        if (tid == 0) {
            float t = 0.f;
            for (int i = 0; i < 16; i++) t += ls[i];
            *normsum = t;
        }
        return;
    }

    __shared__ unsigned int hist[NCOPY * HSTRIDE];   // 48 KB
    __shared__ unsigned int waveSums[16];
    __shared__ unsigned int selBin, selBase;
    const int b = blockIdx.x;
    const int lane = tid & 63, wid = tid >> 6;
    const int hc = (wid % NCOPY) * HSTRIDE;          // this wave's hist copy base

    const unsigned int wc = wcnt[b * 16];
    const unsigned int Ch = chib[b * 16];
    const int fb = (wc > WCAP) || (Ch >= RSEL) || (Ch + wc < RSEL);
    unsigned int target = fb ? RSEL : (RSEL - Ch);
    const unsigned int wcg = (wc > WCAP) ? WCAP : wc;
    const unsigned int* wp = wu + (size_t)b * WCAP;
    const float* Yb = Y + (size_t)b * MTOT;

    unsigned int d1 = 0, d2 = 0;

    for (int level = 0; level < 3; level++) {
        const int nb  = (level < 2) ? 4096 : 256;
        const int bpt = (level < 2) ? 4 : 1;
        for (int i = tid; i < NCOPY * HSTRIDE; i += 1024) hist[i] = 0u;
        if (tid == 0) { selBin = 0u; selBase = 0u; }
        __syncthreads();

#define HISTO(u) do { \
            if (level == 0) atomicAdd(&hist[hc + ((u) >> 20)], 1u); \
            else if (level == 1) { if (((u) >> 20) == d1) atomicAdd(&hist[hc + (((u) >> 8) & 0xFFFu)], 1u); } \
            else { if (((u) >> 8) == ((d1 << 12) | d2)) atomicAdd(&hist[hc + ((u) & 0xFFu)], 1u); } \
        } while (0)

        if (fb) {
            for (unsigned int i = tid; i < (unsigned int)MTOT; i += 1024u) {
                unsigned int u = fmap(Yb[i]);
                HISTO(u);
            }
        } else {
            for (unsigned int i = tid; i < wcg; i += 1024u) {
                unsigned int u = wp[i];
                HISTO(u);
            }
        }
#undef HISTO
        __syncthreads();
        // descending scan + pick (merge the 3 copies at read time)
        unsigned int c[4] = {0u, 0u, 0u, 0u};
        unsigned int s = 0u;
        const int nthr = nb / bpt;
        if (tid < nthr)
            for (int k = 0; k < bpt; k++) {
                int bin = nb - 1 - (tid * bpt + k);
                c[k] = hist[bin] + hist[HSTRIDE + bin] + hist[2 * HSTRIDE + bin];
                s += c[k];
            }
        unsigned int incl = s;
        for (int d = 1; d < 64; d <<= 1) {
            unsigned int v = __shfl_up(incl, d);
            if (lane >= d) incl += v;
        }
        if (lane == 63) waveSums[wid] = incl;
        __syncthreads();
        if (tid < 16) {
            unsigned int w = waveSums[tid];
            for (int d = 1; d < 16; d <<= 1) {
                unsigned int v = __shfl_up(w, d);
                if (tid >= d) w += v;
            }
            waveSums[tid] = w;
        }
        __syncthreads();
        incl += (wid > 0) ? waveSums[wid - 1] : 0u;
        unsigned int excl = incl - s;
        if (s > 0u && excl < target && incl >= target) {
            unsigned int run = excl;
            for (int k = 0; k < bpt; k++) {
                if (run + c[k] >= target) {
                    selBin = (unsigned int)(nb - 1 - (tid * bpt + k));
                    selBase = run;
                    break;
                }
                run += c[k];
            }
        }
        __syncthreads();
        if (level == 0) d1 = selBin;
        else if (level == 1) d2 = selBin;
        target -= selBase;
        __syncthreads();
    }
    if (tid == 0) {
        thr[b] = (d1 << 20) | (d2 << 8) | selBin;
        fbflag[b] = (unsigned int)fb;
    }
}

// ---- K3: blocks [0,2048) Z0 write; blocks [2048,4096) window fixup
// (or per-batch full re-threshold if that batch hit fallback).
__global__ void fixup_z_kernel(const float* __restrict__ Y,
                               const unsigned int* __restrict__ wu,
                               const unsigned int* __restrict__ wpos,
                               const unsigned int* __restrict__ wcnt,
                               const unsigned int* __restrict__ thr,
                               const unsigned int* __restrict__ fbflag,
                               const float* __restrict__ zabs,
                               const float* __restrict__ zang,
                               const float* __restrict__ normsum,
                               float* __restrict__ out,
                               float* __restrict__ outz, int interleaved) {
    const int tid = threadIdx.x;
    if (blockIdx.x < 2048) {
        int i = blockIdx.x * 256 + tid;              // [0, HH*WW/2)
        float inv = 1.0f / sqrtf(*normsum);
        float2 a = ((const float2*)zabs)[i];
        float2 g = ((const float2*)zang)[i];
        float s0, c0, s1, c1;
        __sincosf(g.x, &s0, &c0);
        __sincosf(g.y, &s1, &c1);
        if (interleaved) {
            float4 o;
            o.x = a.x * c0 * inv; o.y = a.x * s0 * inv;
            o.z = a.y * c1 * inv; o.w = a.y * s1 * inv;
            nt_store4(o, &((float4*)outz)[i]);
        } else {
            float2 o;
            o.x = a.x * c0 * inv; o.y = a.y * c1 * inv;
            nt_store2(o, &((float2*)outz)[i]);
        }
    } else {
        const int j = blockIdx.x - 2048;             // [0, 2048): 256 blocks per batch
        const int b = j >> 8;
        const unsigned int tu = thr[b];
        float* outb = out + (size_t)b * MTOT;
        if (fbflag[b]) {
            // exact fallback: full re-threshold + transpose for this batch
            const float* Yb = Y + (size_t)b * MTOT;
            for (int q = (j & 255); q < 1024; q += 256) {        // 4 sub-rows of work
                int pq = q * 256 + tid;                          // [0, 262144)
                thresh_row_quad(Yb, outb, pq >> 8, pq & 255, tu);
            }
        } else {
            const unsigned int wc = wcnt[b * 16];                // <= WCAP in non-fb mode
            const unsigned int* wub = wu + (size_t)b * WCAP;
            const unsigned int* wpb = wpos + (size_t)b * WCAP;
            for (unsigned int i = (unsigned int)(j & 255) * 256u + tid; i < wc; i += 65536u) {
                unsigned int u = wub[i];
                unsigned int pos = wpb[i];
                outb[pos] = (u >= tu) ? 1.f : 0.f;
            }
        }
    }
}

extern "C" void kernel_launch(void* const* d_in, const int* in_sizes, int n_in,
                              void* d_out, int out_size, void* d_ws, size_t ws_size,
                              hipStream_t stream) {
    const float* Y    = (const float*)d_in[0];
    const float* zabs = (const float*)d_in[1];
    const float* zang = (const float*)d_in[2];
    float* out = (float*)d_out;

    unsigned char* ws = (unsigned char*)d_ws;
    unsigned int* wcnt  = (unsigned int*)(ws + WS_WCNT_OFF);
    unsigned int* chib  = (unsigned int*)(ws + WS_CHI_OFF);
    float*        npart = (float*)(ws + WS_NPART_OFF);
    unsigned int* thr   = (unsigned int*)(ws + WS_THR_OFF);
    unsigned int* fbf   = (unsigned int*)(ws + WS_FB_OFF);
    float*        norm  = (float*)(ws + WS_NORM_OFF);
    unsigned int* wu    = (unsigned int*)(ws + WS_WU_OFF);
    unsigned int* wpos  = (unsigned int*)(ws + WS_WP_OFF);

    // zero the atomic counters (wcnt @0..512, chib @512..1024)
    (void)hipMemsetAsync(ws, 0, 1024, stream);

    pass1_kernel<<<P1B + 256, 256, 0, stream>>>(Y, zabs, out, wu, wpos, wcnt, chib, npart);
    refine_kernel<<<9, 1024, 0, stream>>>(Y, wu, wcnt, chib, npart, thr, fbf, norm);

    size_t zoff = (size_t)BATCH * CC * HH * WW;   // 25165824
    int zfloats = out_size - (int)zoff;
    int interleaved = (zfloats >= 2 * HH * WW) ? 1 : 0;
    fixup_z_kernel<<<2048 + 2048, 256, 0, stream>>>(
        Y, wu, wpos, wcnt, thr, fbf, zabs, zang, norm, out, out + zoff, interleaved);
}

// Round 7
// 244.626 us; speedup vs baseline: 1.0626x; 1.0501x over previous
//
#include <hip/hip_runtime.h>
#include <math.h>

#define BATCH 8
#define HH 1024
#define WW 1024
#define CC 3
#define MTOT (HH*WW*CC)          // 3145728 per batch
#define RSEL 1572864u            // ceil(M/2)

#define WCAP 131072u             // per-batch window record capacity (expect ~39K used)
#define LCAP 1024u               // per-block LDS record capacity (expect ~153 used)
#define P1B  2048                // pass1 threshold blocks (256 per batch)
#define QPT  4                   // pixel-quads per thread (48 floats)

// window: |x| < 2^-6. Median of 3.1M N(0,1) samples is within ~8e-3 (11 sigma).
// Window holds ~39K elems/batch. Exact per-batch fallback in K2/K3 if it ever misses.
#define U_HI 0xBC800000u         // fmap(+2^-6)
#define U_LO 0x437FFFFFu         // fmap(-2^-6)

// ---- ws layout (bytes). wcnt+chib (first 1024 B) need zero-init; rest written unconditionally.
#define WS_WCNT_OFF  0u          // 8 u32 @ stride 64B : per-batch window counts (atomic)
#define WS_CHI_OFF   512u        // 8 u32 @ stride 64B : per-batch high counts (atomic)
#define WS_NPART_OFF 1024u       // 256 f32 : znorm partials
#define WS_THR_OFF   2048u       // 8 u32 : thresholds (u-space)
#define WS_FB_OFF    2112u       // 8 u32 : per-batch fallback flags
#define WS_WU_OFF    4096u       // 8*WCAP u32 = 4 MB window u-values (SoA)
#define WS_WP_OFF    4198400u    // 8*WCAP u32 = 4 MB window output positions (SoA)

// refine: 3 wave-privatized histogram copies, +1 stride to decorrelate banks
#define NCOPY 3
#define HSTRIDE 4097

__device__ __forceinline__ unsigned int fmap(float x) {
    unsigned int b = __float_as_uint(x);
    return (b & 0x80000000u) ? ~b : (b | 0x80000000u);
}

// Shared transpose-threshold body for K3's exact fallback path.
__device__ __forceinline__ void thresh_row_quad(const float* __restrict__ Yb,
                                                float* __restrict__ outb,
                                                int h, int w4, unsigned int tu) {
    const float4* src = (const float4*)(Yb + ((size_t)h * WW + (size_t)w4 * 4) * CC);
    float4 a0 = src[0], a1 = src[1], a2 = src[2];
    float4 r0, r1, r2;
    r0.x = (fmap(a0.x) >= tu) ? 1.f : 0.f;
    r0.y = (fmap(a0.w) >= tu) ? 1.f : 0.f;
    r0.z = (fmap(a1.z) >= tu) ? 1.f : 0.f;
    r0.w = (fmap(a2.y) >= tu) ? 1.f : 0.f;
    r1.x = (fmap(a0.y) >= tu) ? 1.f : 0.f;
    r1.y = (fmap(a1.x) >= tu) ? 1.f : 0.f;
    r1.z = (fmap(a1.w) >= tu) ? 1.f : 0.f;
    r1.w = (fmap(a2.z) >= tu) ? 1.f : 0.f;
    r2.x = (fmap(a0.z) >= tu) ? 1.f : 0.f;
    r2.y = (fmap(a1.y) >= tu) ? 1.f : 0.f;
    r2.z = (fmap(a2.x) >= tu) ? 1.f : 0.f;
    r2.w = (fmap(a2.w) >= tu) ? 1.f : 0.f;
    size_t base = (size_t)h * WW;
    ((float4*)(outb + base))[w4]                        = r0;
    ((float4*)(outb + base + (size_t)HH * WW))[w4]      = r1;
    ((float4*)(outb + base + (size_t)2 * HH * WW))[w4]  = r2;
}

// ---- K1: single full pass over Y, two-phase (streaming path atomic-free).
// Phase A: 12 loads up-front (sched_barrier-pinned), classify 48 elems into a
// u64 window mask, store speculative outputs (REGULAR stores this round: A/B
// vs R6's NT stores — fills prove the cached write path sustains 5.6+ TB/s,
// and out+Y both fit L3 so Y residency is preserved either way).
// Phase B (rare): one LDS atomicAdd per thread-with-hits + static record emit.
// Blocks [P1B,P1B+256): znorm partials over zabs.
__global__ void __launch_bounds__(256, 4) pass1_kernel(
                             const float* __restrict__ Y,
                             const float* __restrict__ zabs,
                             float* __restrict__ out,
                             unsigned int* __restrict__ wu,
                             unsigned int* __restrict__ wpos,
                             unsigned int* __restrict__ wcnt,
                             unsigned int* __restrict__ chib,
                             float* __restrict__ npart) {
    const int tid = threadIdx.x;

    if (blockIdx.x >= P1B) {
        // znorm partial: sum zabs^2 over HH*WW, one partial per block (256 blocks)
        const int bx = blockIdx.x - P1B;
        float s = 0.f;
        const int n4z = HH * WW / 4;                 // 262144
        for (int i = bx * 256 + tid; i < n4z; i += 256 * 256) {  // 4 iters
            float4 v = ((const float4*)zabs)[i];
            s += v.x * v.x + v.y * v.y + v.z * v.z + v.w * v.w;
        }
        for (int d = 32; d > 0; d >>= 1) s += __shfl_down(s, d);
        __shared__ float ls[4];
        if ((tid & 63) == 0) ls[tid >> 6] = s;
        __syncthreads();
        if (tid == 0) npart[bx] = ls[0] + ls[1] + ls[2] + ls[3];
        return;
    }

    __shared__ unsigned int lu[LCAP];
    __shared__ unsigned int lp[LCAP];
    __shared__ unsigned int lcnt;
    __shared__ unsigned int red[4];
    __shared__ unsigned int gbase_s;
    if (tid == 0) lcnt = 0u;
    __syncthreads();

    const int blk = blockIdx.x;                      // [0, P1B): 256 blocks per batch
    const int b = blk >> 8;                          // block-uniform
    const int p0 = (blk & 255) * 1024 + tid;         // within-batch quad index base
    const float* Yb = Y + (size_t)b * MTOT;
    float* outb = out + (size_t)b * MTOT;
    float4* o4 = (float4*)outb;

    // ---- Phase A: issue all 12 loads before any use; pin with sched_barrier
    float4 A0[QPT], A1[QPT], A2[QPT];
#pragma unroll
    for (int it = 0; it < QPT; it++) {
        int p = p0 + it * 256;
        const float4* src = (const float4*)(Yb + (size_t)p * 12);
        A0[it] = src[0]; A1[it] = src[1]; A2[it] = src[2];
    }
    __builtin_amdgcn_sched_barrier(0);

    unsigned int hcnt = 0u;
    unsigned long long wmask = 0ull;

#pragma unroll
    for (int it = 0; it < QPT; it++) {
        const int p = p0 + it * 256;
        float4 a0 = A0[it], a1 = A1[it], a2 = A2[it];
        float4 r0, r1, r2;

#define CLS(val, dst, j) do { \
        unsigned int u = fmap(val); \
        bool hi = (u >= U_HI); \
        dst = hi ? 1.f : 0.f; \
        hcnt += hi ? 1u : 0u; \
        if (!hi && u >= U_LO) wmask |= (1ull << (it * 12 + (j))); \
    } while (0)

        CLS(a0.x, r0.x, 0); CLS(a0.w, r0.y, 1); CLS(a1.z, r0.z, 2); CLS(a2.y, r0.w, 3);
        CLS(a0.y, r1.x, 4); CLS(a1.x, r1.y, 5); CLS(a1.w, r1.z, 6); CLS(a2.z, r1.w, 7);
        CLS(a0.z, r2.x, 8); CLS(a1.y, r2.y, 9); CLS(a2.x, r2.z, 10); CLS(a2.w, r2.w, 11);
#undef CLS

        o4[p]           = r0;
        o4[262144 + p]  = r1;
        o4[524288 + p]  = r2;
    }

    // ---- Phase B: rare record emit (~38 threads/block enter), one atomic each
    if (wmask) {
        unsigned int nw = (unsigned int)__popcll(wmask);
        unsigned int base = atomicAdd(&lcnt, nw);
#pragma unroll
        for (int it = 0; it < QPT; it++) {
            const int p = p0 + it * 256;
            const unsigned int rb = (unsigned int)(4 * p);
            float4 a0 = A0[it], a1 = A1[it], a2 = A2[it];
#define EMIT(val, ch, k, j) do { \
            if (wmask & (1ull << (it * 12 + (j)))) { \
                if (base < LCAP) { lu[base] = fmap(val); lp[base] = (unsigned int)((ch) * HH * WW) + rb + (k); } \
                base++; \
            } \
        } while (0)
            EMIT(a0.x, 0, 0, 0); EMIT(a0.w, 0, 1, 1); EMIT(a1.z, 0, 2, 2); EMIT(a2.y, 0, 3, 3);
            EMIT(a0.y, 1, 0, 4); EMIT(a1.x, 1, 1, 5); EMIT(a1.w, 1, 2, 6); EMIT(a2.z, 1, 3, 7);
            EMIT(a0.z, 2, 0, 8); EMIT(a1.y, 2, 1, 9); EMIT(a2.x, 2, 2, 10); EMIT(a2.w, 2, 3, 11);
#undef EMIT
        }
    }

    // block reductions: one global atomic each for count + high-count
    __syncthreads();
    unsigned int n = lcnt;                           // block-uniform
    unsigned int nc = (n > LCAP) ? LCAP : n;
    if (tid == 0) {
        // overflow (never expected: mean 153, cap 1024) poisons wcnt -> fallback
        unsigned int add = (n > LCAP) ? (WCAP + 1u) : n;
        gbase_s = atomicAdd(&wcnt[b * 16], add);
    }
    for (int d = 32; d > 0; d >>= 1) hcnt += __shfl_down(hcnt, d);
    if ((tid & 63) == 0) red[tid >> 6] = hcnt;
    __syncthreads();
    if (tid == 0) atomicAdd(&chib[b * 16], red[0] + red[1] + red[2] + red[3]);

    unsigned int gbase = gbase_s;
    unsigned int* wub = wu + (size_t)b * WCAP;
    unsigned int* wpb = wpos + (size_t)b * WCAP;
    for (unsigned int j = tid; j < nc; j += 256u) {
        unsigned int q = gbase + j;
        if (q < WCAP) { wub[q] = lu[j]; wpb[q] = lp[j]; }
    }
}

// ---- K2: blocks 0..7 = per-batch 3-level radix select (3-copy privatized
// hist); blocks 8..519 = Z0 write running CONCURRENTLY on the otherwise-idle
// CUs (each Z0 block inlines the 256-element norm reduce — no finalize dep).
__global__ void __launch_bounds__(1024) refine_kernel(
        const float* __restrict__ Y,
        const unsigned int* __restrict__ wu,
        const unsigned int* __restrict__ wcnt,
        const unsigned int* __restrict__ chib,
        const float* __restrict__ npart,
        unsigned int* __restrict__ thr,
        unsigned int* __restrict__ fbflag,
        const float* __restrict__ zabs,
        const float* __restrict__ zang,
        float* __restrict__ outz, int interleaved) {
    const int tid = threadIdx.x;

    if (blockIdx.x >= 8) {
        // Z0 write: 512 blocks x 1024 threads, one float2-pair each
        const int z = blockIdx.x - 8;
        __shared__ float ls[4];
        float s = (tid < 256) ? npart[tid] : 0.f;
        for (int d = 32; d > 0; d >>= 1) s += __shfl_down(s, d);
        if (tid < 256 && (tid & 63) == 0) ls[tid >> 6] = s;
        __syncthreads();
        float inv = 1.0f / sqrtf(ls[0] + ls[1] + ls[2] + ls[3]);
        int i = z * 1024 + tid;                      // [0, HH*WW/2)
        float2 a = ((const float2*)zabs)[i];
        float2 g = ((const float2*)zang)[i];
        float s0, c0, s1, c1;
        __sincosf(g.x, &s0, &c0);
        __sincosf(g.y, &s1, &c1);
        if (interleaved) {
            float4 o;
            o.x = a.x * c0 * inv; o.y = a.x * s0 * inv;
            o.z = a.y * c1 * inv; o.w = a.y * s1 * inv;
            ((float4*)outz)[i] = o;
        } else {
            float2 o;
            o.x = a.x * c0 * inv; o.y = a.y * c1 * inv;
            ((float2*)outz)[i] = o;
        }
        return;
    }

    __shared__ unsigned int hist[NCOPY * HSTRIDE];   // 48 KB
    __shared__ unsigned int waveSums[16];
    __shared__ unsigned int selBin, selBase;
    const int b = blockIdx.x;
    const int lane = tid & 63, wid = tid >> 6;
    const int hc = (wid % NCOPY) * HSTRIDE;          // this wave's hist copy base

    const unsigned int wc = wcnt[b * 16];
    const unsigned int Ch = chib[b * 16];
    const int fb = (wc > WCAP) || (Ch >= RSEL) || (Ch + wc < RSEL);
    unsigned int target = fb ? RSEL : (RSEL - Ch);
    const unsigned int wcg = (wc > WCAP) ? WCAP : wc;
    const unsigned int* wp = wu + (size_t)b * WCAP;
    const float* Yb = Y + (size_t)b * MTOT;

    unsigned int d1 = 0, d2 = 0;

    for (int level = 0; level < 3; level++) {
        const int nb  = (level < 2) ? 4096 : 256;
        const int bpt = (level < 2) ? 4 : 1;
        for (int i = tid; i < NCOPY * HSTRIDE; i += 1024) hist[i] = 0u;
        if (tid == 0) { selBin = 0u; selBase = 0u; }
        __syncthreads();

#define HISTO(u) do { \
            if (level == 0) atomicAdd(&hist[hc + ((u) >> 20)], 1u); \
            else if (level == 1) { if (((u) >> 20) == d1) atomicAdd(&hist[hc + (((u) >> 8) & 0xFFFu)], 1u); } \
            else { if (((u) >> 8) == ((d1 << 12) | d2)) atomicAdd(&hist[hc + ((u) & 0xFFu)], 1u); } \
        } while (0)

        if (fb) {
            for (unsigned int i = tid; i < (unsigned int)MTOT; i += 1024u) {
                unsigned int u = fmap(Yb[i]);
                HISTO(u);
            }
        } else {
            for (unsigned int i = tid; i < wcg; i += 1024u) {
                unsigned int u = wp[i];
                HISTO(u);
            }
        }
#undef HISTO
        __syncthreads();
        // descending scan + pick (merge the 3 copies at read time)
        unsigned int c[4] = {0u, 0u, 0u, 0u};
        unsigned int s = 0u;
        const int nthr = nb / bpt;
        if (tid < nthr)
            for (int k = 0; k < bpt; k++) {
                int bin = nb - 1 - (tid * bpt + k);
                c[k] = hist[bin] + hist[HSTRIDE + bin] + hist[2 * HSTRIDE + bin];
                s += c[k];
            }
        unsigned int incl = s;
        for (int d = 1; d < 64; d <<= 1) {
            unsigned int v = __shfl_up(incl, d);
            if (lane >= d) incl += v;
        }
        if (lane == 63) waveSums[wid] = incl;
        __syncthreads();
        if (tid < 16) {
            unsigned int w = waveSums[tid];
            for (int d = 1; d < 16; d <<= 1) {
                unsigned int v = __shfl_up(w, d);
                if (tid >= d) w += v;
            }
            waveSums[tid] = w;
        }
        __syncthreads();
        incl += (wid > 0) ? waveSums[wid - 1] : 0u;
        unsigned int excl = incl - s;
        if (s > 0u && excl < target && incl >= target) {
            unsigned int run = excl;
            for (int k = 0; k < bpt; k++) {
                if (run + c[k] >= target) {
                    selBin = (unsigned int)(nb - 1 - (tid * bpt + k));
                    selBase = run;
                    break;
                }
                run += c[k];
            }
        }
        __syncthreads();
        if (level == 0) d1 = selBin;
        else if (level == 1) d2 = selBin;
        target -= selBase;
        __syncthreads();
    }
    if (tid == 0) {
        thr[b] = (d1 << 20) | (d2 << 8) | selBin;
        fbflag[b] = (unsigned int)fb;
    }
}

// ---- K3: scatter-only window fixup, 256 blocks (32/batch); per-batch full
// re-threshold fallback if the window missed the rank.
__global__ void fixup_kernel(const float* __restrict__ Y,
                             const unsigned int* __restrict__ wu,
                             const unsigned int* __restrict__ wpos,
                             const unsigned int* __restrict__ wcnt,
                             const unsigned int* __restrict__ thr,
                             const unsigned int* __restrict__ fbflag,
                             float* __restrict__ out) {
    const int tid = threadIdx.x;
    const int j = blockIdx.x;                        // [0, 256): 32 blocks per batch
    const int b = j >> 5;
    const unsigned int tu = thr[b];
    float* outb = out + (size_t)b * MTOT;
    if (fbflag[b]) {
        // exact fallback: full re-threshold + transpose for this batch
        const float* Yb = Y + (size_t)b * MTOT;
        for (int q = (j & 31) * 256 + tid; q < 262144; q += 8192) {
            thresh_row_quad(Yb, outb, q >> 8, q & 255, tu);
        }
    } else {
        const unsigned int wc = wcnt[b * 16];        // <= WCAP in non-fb mode
        const unsigned int* wub = wu + (size_t)b * WCAP;
        const unsigned int* wpb = wpos + (size_t)b * WCAP;
        for (unsigned int i = (unsigned int)(j & 31) * 256u + tid; i < wc; i += 8192u) {
            outb[wpb[i]] = (wub[i] >= tu) ? 1.f : 0.f;
        }
    }
}

extern "C" void kernel_launch(void* const* d_in, const int* in_sizes, int n_in,
                              void* d_out, int out_size, void* d_ws, size_t ws_size,
                              hipStream_t stream) {
    const float* Y    = (const float*)d_in[0];
    const float* zabs = (const float*)d_in[1];
    const float* zang = (const float*)d_in[2];
    float* out = (float*)d_out;

    unsigned char* ws = (unsigned char*)d_ws;
    unsigned int* wcnt  = (unsigned int*)(ws + WS_WCNT_OFF);
    unsigned int* chib  = (unsigned int*)(ws + WS_CHI_OFF);
    float*        npart = (float*)(ws + WS_NPART_OFF);
    unsigned int* thr   = (unsigned int*)(ws + WS_THR_OFF);
    unsigned int* fbf   = (unsigned int*)(ws + WS_FB_OFF);
    unsigned int* wu    = (unsigned int*)(ws + WS_WU_OFF);
    unsigned int* wpos  = (unsigned int*)(ws + WS_WP_OFF);

    // zero the atomic counters (wcnt @0..512, chib @512..1024)
    (void)hipMemsetAsync(ws, 0, 1024, stream);

    pass1_kernel<<<P1B + 256, 256, 0, stream>>>(Y, zabs, out, wu, wpos, wcnt, chib, npart);

    size_t zoff = (size_t)BATCH * CC * HH * WW;   // 25165824
    int zfloats = out_size - (int)zoff;
    int interleaved = (zfloats >= 2 * HH * WW) ? 1 : 0;

    refine_kernel<<<8 + 512, 1024, 0, stream>>>(
        Y, wu, wcnt, chib, npart, thr, fbf, zabs, zang, out + zoff, interleaved);

    fixup_kernel<<<256, 256, 0, stream>>>(Y, wu, wpos, wcnt, thr, fbf, out);
}